// Round 2
// baseline (1100.804 us; speedup 1.0000x reference)
//
#include <hip/hip_runtime.h>

// Problem constants
#define N_NODES 50000
#define N_EDGES 600000
#define NPAD    50048          // 782*64 = 391*128, padded row count for tiled GEMMs
#define NBLK_SCAN 196          // ceil(50000/256)

static __device__ __forceinline__ float lrelu(float v) {
    return v > 0.f ? v : 0.01f * v;
}

// ---------------------------------------------------------------------------
// proj768_wave: [N,768] @ [768,NCOLS] for des (25) and tweet (28), one
// dispatch (blockIdx.z selects matrix).
// Round-1 LDS version was barrier-lockstep-bound (block __syncthreads per
// K-tile -> VALU 12.7%). This version has NO barrier in the K-loop:
//   - staging is WAVE-PRIVATE: each wave owns 64 rows and an 8.3KB LDS
//     region; ds_write->ds_read within a wave needs no block sync
//   - K split across wave pairs (wave0: k<384, wave1: k>=384, same rows);
//     one __syncthreads + LDS combine at the very end only
//   - 3128 waves (~3/SIMD): independent waves hide each other's staging
//   - global loads coalesced: per instr 8 rows x 128B (16 lines, fully
//     consumed) vs v4's 64 lines/instr
//   - k and col set wave-uniform -> W/bias stay s_load (scalar) operands
// ---------------------------------------------------------------------------
#define PW_STRIDE 65                 // LDS words per k-row (64 rows + 1 pad)
#define PW_WORDS  (32 * PW_STRIDE)   // 2080 words per wave region

template<int NC>
__device__ __forceinline__ void proj_wave_body(
    const float* __restrict__ A, const float* __restrict__ W,
    const float* __restrict__ bias, float* __restrict__ X0,
    int colbase, float* __restrict__ lbuf, float* __restrict__ pbuf,
    int r0, int khalf, int lane)
{
    float acc[NC];
    #pragma unroll
    for (int c = 0; c < NC; c++) acc[c] = 0.f;

    const int srowb = lane >> 3;     // staging row offset within 8-row group
    const int sf4   = lane & 7;      // staging float4 index within 32-k tile

    for (int kt = 0; kt < 12; kt++) {
        const int k0 = khalf * 384 + kt * 32;
        // ---- stage 64 rows x 32 k, coalesced (8 lanes per row) ----
        float4 v[8];
        #pragma unroll
        for (int i = 0; i < 8; i++) {
            int gr = r0 + i * 8 + srowb;
            if (gr >= N_NODES) gr = N_NODES - 1;   // pad rows: discarded later
            v[i] = *(const float4*)&A[(size_t)gr * 768 + k0 + sf4 * 4];
        }
        #pragma unroll
        for (int i = 0; i < 8; i++) {
            int r = i * 8 + srowb;
            lbuf[(sf4 * 4 + 0) * PW_STRIDE + r] = v[i].x;
            lbuf[(sf4 * 4 + 1) * PW_STRIDE + r] = v[i].y;
            lbuf[(sf4 * 4 + 2) * PW_STRIDE + r] = v[i].z;
            lbuf[(sf4 * 4 + 3) * PW_STRIDE + r] = v[i].w;
        }
        // ---- compute: lane owns one row; w loads wave-uniform (s_load) ----
        #pragma unroll
        for (int k = 0; k < 32; k++) {
            float a = lbuf[k * PW_STRIDE + lane];
            const float* w = W + (size_t)(k0 + k) * NC;
            #pragma unroll
            for (int c = 0; c < NC; c++) acc[c] += a * w[c];
        }
    }

    // ---- combine K halves: odd wave dumps partials, even wave finishes ----
    if (khalf == 1) {
        #pragma unroll
        for (int c = 0; c < NC; c++) pbuf[lane * 29 + c] = acc[c];
    }
    __syncthreads();
    if (khalf == 0) {
        int gr = r0 + lane;
        if (gr < N_NODES) {
            #pragma unroll
            for (int c = 0; c < NC; c++) {
                float sv = acc[c] + pbuf[lane * 29 + c] + bias[c];
                X0[(size_t)gr * 128 + colbase + c] = lrelu(sv);
            }
        }
    }
}

__global__ __launch_bounds__(256) void proj768_wave(
    const float* __restrict__ des, const float* __restrict__ Wd, const float* __restrict__ bd,
    const float* __restrict__ tw,  const float* __restrict__ Wt, const float* __restrict__ bt,
    float* __restrict__ X0)
{
    __shared__ float buf[4 * PW_WORDS];          // 33.3 KB: 4 wave-private regions
    const int t    = threadIdx.x;
    const int wv   = t >> 6, lane = t & 63;
    const int rowhalf = wv >> 1, khalf = wv & 1;
    const int r0   = blockIdx.x * 128 + rowhalf * 64;
    float* lbuf = buf + wv * PW_WORDS;
    float* pbuf = buf + (wv | 1) * PW_WORDS;     // odd wave's region holds partials
    if (blockIdx.z == 0) proj_wave_body<25>(des, Wd, bd, X0, 0,  lbuf, pbuf, r0, khalf, lane);
    else                 proj_wave_body<28>(tw, Wt, bt, X0, 25, lbuf, pbuf, r0, khalf, lane);
}

// ---------------------------------------------------------------------------
// Small projections: num (K=7 -> cols 53..77), cat (K=11 -> 78..102),
// new_feature (K=1 -> 103..127). One thread per (node, out-col).
// ---------------------------------------------------------------------------
__global__ void small_proj_kernel(
    const float* __restrict__ nump, const float* __restrict__ catp, const float* __restrict__ newf,
    const float* __restrict__ Wn, const float* __restrict__ bn,
    const float* __restrict__ Wc, const float* __restrict__ bc,
    const float* __restrict__ Ww, const float* __restrict__ bw,
    float* __restrict__ out)
{
    int id = blockIdx.x * 256 + threadIdx.x;
    int n = id / 75, c = id % 75;
    if (n >= N_NODES) return;
    float acc; int col;
    if (c < 25) {
        col = 53 + c; acc = bn[c];
        #pragma unroll
        for (int k = 0; k < 7; k++) acc += nump[n * 7 + k] * Wn[k * 25 + c];
    } else if (c < 50) {
        int cc = c - 25; col = 78 + cc; acc = bc[cc];
        #pragma unroll
        for (int k = 0; k < 11; k++) acc += catp[n * 11 + k] * Wc[k * 25 + cc];
    } else {
        int cc = c - 50; col = 103 + cc;
        acc = bw[cc] + newf[n] * Ww[cc];
    }
    out[(size_t)n * 128 + col] = lrelu(acc);
}

// ---------------------------------------------------------------------------
// gemm_v2: tiled fp32 GEMM, 128 out cols. Tile 128 rows x 128 cols, K-tile 32.
// 256 threads as 16x16, 8x8 micro-tile. A stored TRANSPOSED in LDS so the
// inner loop is pure ds_read_b128.
// SPLIT: A = [S (256 wide) | A2 (128 wide)], B = [rel_w (256 rows); root_w].
// ---------------------------------------------------------------------------
template<int KTOT, bool SPLIT, bool ACT>
__global__ __launch_bounds__(256, 4) void gemm_v2(
    const float* __restrict__ A, const float* __restrict__ A2,
    const float* __restrict__ B, const float* __restrict__ B2,
    const float* __restrict__ bias, float* __restrict__ out)
{
    __shared__ float AlT[32 * 132];   // [k][row], row-padded stride 132
    __shared__ float Bl [32 * 132];   // [k][col]
    const int t  = threadIdx.x;
    const int r0 = blockIdx.x * 128;
    const int tx = t & 15, ty = t >> 4;

    float acc[8][8] = {};

    for (int k0 = 0; k0 < KTOT; k0 += 32) {
        // A tile: 128 rows x 32 k = 1024 float4, 4 per thread, store transposed
        #pragma unroll
        for (int i = 0; i < 4; i++) {
            int f4i = t + i * 256;
            int row = f4i >> 3, c4 = f4i & 7;
            int k = k0 + c4 * 4;
            float4 v;
            if (!SPLIT) {
                v = *(const float4*)&A[(size_t)(r0 + row) * 128 + k];
            } else {
                if (k < 256) v = *(const float4*)&A[(size_t)(r0 + row) * 256 + k];
                else         v = *(const float4*)&A2[(size_t)(r0 + row) * 128 + (k - 256)];
            }
            AlT[(c4 * 4 + 0) * 132 + row] = v.x;
            AlT[(c4 * 4 + 1) * 132 + row] = v.y;
            AlT[(c4 * 4 + 2) * 132 + row] = v.z;
            AlT[(c4 * 4 + 3) * 132 + row] = v.w;
        }
        // B tile: 32 k x 128 cols = 1024 float4, 4 per thread
        #pragma unroll
        for (int i = 0; i < 4; i++) {
            int f4i = t + i * 256;
            int kk = f4i >> 5, c4 = f4i & 31;
            int k = k0 + kk;
            float4 v;
            if (!SPLIT) v = *(const float4*)&B[(size_t)k * 128 + c4 * 4];
            else v = (k < 256) ? *(const float4*)&B[(size_t)k * 128 + c4 * 4]
                               : *(const float4*)&B2[(size_t)(k - 256) * 128 + c4 * 4];
            *(float4*)&Bl[kk * 132 + c4 * 4] = v;
        }
        __syncthreads();
        #pragma unroll 4
        for (int k = 0; k < 32; k++) {
            float4 a0 = *(const float4*)&AlT[k * 132 + ty * 8];
            float4 a1 = *(const float4*)&AlT[k * 132 + ty * 8 + 4];
            float4 b0 = *(const float4*)&Bl [k * 132 + tx * 8];
            float4 b1 = *(const float4*)&Bl [k * 132 + tx * 8 + 4];
            float av[8] = {a0.x, a0.y, a0.z, a0.w, a1.x, a1.y, a1.z, a1.w};
            float bv[8] = {b0.x, b0.y, b0.z, b0.w, b1.x, b1.y, b1.z, b1.w};
            #pragma unroll
            for (int i = 0; i < 8; i++)
                #pragma unroll
                for (int j = 0; j < 8; j++) acc[i][j] += av[i] * bv[j];
        }
        __syncthreads();
    }
    float4 bb0 = *(const float4*)&bias[tx * 8];
    float4 bb1 = *(const float4*)&bias[tx * 8 + 4];
    float bb[8] = {bb0.x, bb0.y, bb0.z, bb0.w, bb1.x, bb1.y, bb1.z, bb1.w};
    #pragma unroll
    for (int i = 0; i < 8; i++) {
        size_t row = (size_t)(r0 + ty * 8 + i);
        float o[8];
        #pragma unroll
        for (int j = 0; j < 8; j++) {
            o[j] = acc[i][j] + bb[j];
            if (ACT) o[j] = lrelu(o[j]);
        }
        *(float4*)&out[row * 128 + tx * 8]     = make_float4(o[0], o[1], o[2], o[3]);
        *(float4*)&out[row * 128 + tx * 8 + 4] = make_float4(o[4], o[5], o[6], o[7]);
    }
}

// ---------------------------------------------------------------------------
// CSR build: count, 3-phase exclusive scan, fill (type packed into sign bit).
// ---------------------------------------------------------------------------
__global__ void count_kernel(const int* __restrict__ ei, int* __restrict__ count) {
    int e = blockIdx.x * 256 + threadIdx.x;
    if (e < N_EDGES) atomicAdd(&count[ei[N_EDGES + e]], 1);
}

__global__ void scan1_kernel(const int* __restrict__ count, int* __restrict__ partial) {
    __shared__ int sm[256];
    int b = blockIdx.x, t = threadIdx.x;
    int i = b * 256 + t;
    sm[t] = (i < N_NODES) ? count[i] : 0;
    __syncthreads();
    for (int off = 128; off > 0; off >>= 1) {
        if (t < off) sm[t] += sm[t + off];
        __syncthreads();
    }
    if (t == 0) partial[b] = sm[0];
}

__global__ void scan2_kernel(int* __restrict__ partial) {
    __shared__ int sm[256];
    int t = threadIdx.x;
    int v = (t < NBLK_SCAN) ? partial[t] : 0;
    sm[t] = v; __syncthreads();
    for (int off = 1; off < 256; off <<= 1) {
        int add = (t >= off) ? sm[t - off] : 0;
        __syncthreads();
        sm[t] += add;
        __syncthreads();
    }
    partial[t] = sm[t] - v;   // exclusive
}

__global__ void scan3_kernel(const int* __restrict__ count, const int* __restrict__ partial,
                             int* __restrict__ offsets) {
    __shared__ int sm[256];
    int b = blockIdx.x, t = threadIdx.x;
    int i = b * 256 + t;
    int v = (i < N_NODES) ? count[i] : 0;
    sm[t] = v; __syncthreads();
    for (int off = 1; off < 256; off <<= 1) {
        int add = (t >= off) ? sm[t - off] : 0;
        __syncthreads();
        sm[t] += add;
        __syncthreads();
    }
    if (i < N_NODES) offsets[i] = partial[b] + sm[t] - v;
}

__global__ void fill_kernel(const int* __restrict__ ei, const int* __restrict__ et,
                            const int* __restrict__ offsets, int* __restrict__ cursor,
                             int* __restrict__ elist) {
    int e = blockIdx.x * 256 + threadIdx.x;
    if (e < N_EDGES) {
        int d = ei[N_EDGES + e];
        int pos = atomicAdd(&cursor[d], 1);
        elist[offsets[d] + pos] = (int)(((unsigned)ei[e]) | (((unsigned)et[e]) << 31));
    }
}

// ---------------------------------------------------------------------------
// aggregate_v3: s[n][r][:] = (1/max(deg,1)) * sum_{e:type=r} x[src_e][:]
// 32 lanes per node (float4 each), 8 nodes per 256-thread block.
// 2-edge unroll for memory-level parallelism.
// ---------------------------------------------------------------------------
__global__ __launch_bounds__(256) void aggregate_v3(
    const float* __restrict__ x, const int* __restrict__ offsets,
    const int* __restrict__ count, const int* __restrict__ elist,
    float* __restrict__ s)
{
    int nid  = blockIdx.x * 8 + (threadIdx.x >> 5);
    int lane = threadIdx.x & 31;
    if (nid >= N_NODES) return;
    int start = offsets[nid], dg = count[nid];
    float4 a0 = make_float4(0.f, 0.f, 0.f, 0.f);
    float4 a1 = make_float4(0.f, 0.f, 0.f, 0.f);
    int i = 0;
    for (; i + 2 <= dg; i += 2) {
        int v0 = elist[start + i];
        int v1 = elist[start + i + 1];
        float4 u = ((const float4*)&x[(size_t)(v0 & 0x7FFFFFFF) * 128])[lane];
        float4 w = ((const float4*)&x[(size_t)(v1 & 0x7FFFFFFF) * 128])[lane];
        if (v0 < 0) { a1.x += u.x; a1.y += u.y; a1.z += u.z; a1.w += u.w; }
        else        { a0.x += u.x; a0.y += u.y; a0.z += u.z; a0.w += u.w; }
        if (v1 < 0) { a1.x += w.x; a1.y += w.y; a1.z += w.z; a1.w += w.w; }
        else        { a0.x += w.x; a0.y += w.y; a0.z += w.z; a0.w += w.w; }
    }
    if (i < dg) {
        int v0 = elist[start + i];
        float4 u = ((const float4*)&x[(size_t)(v0 & 0x7FFFFFFF) * 128])[lane];
        if (v0 < 0) { a1.x += u.x; a1.y += u.y; a1.z += u.z; a1.w += u.w; }
        else        { a0.x += u.x; a0.y += u.y; a0.z += u.z; a0.w += u.w; }
    }
    float inv = 1.0f / (float)(dg > 0 ? dg : 1);
    a0.x *= inv; a0.y *= inv; a0.z *= inv; a0.w *= inv;
    a1.x *= inv; a1.y *= inv; a1.z *= inv; a1.w *= inv;
    ((float4*)&s[(size_t)nid * 256])[lane]       = a0;
    ((float4*)&s[(size_t)nid * 256 + 128])[lane] = a1;
}

// ---------------------------------------------------------------------------
// Final: out[n][0:2] = x4[n] @ W_out2 + b_out2. One wave per node.
// ---------------------------------------------------------------------------
__global__ __launch_bounds__(64) void final_kernel(
    const float* __restrict__ x, const float* __restrict__ W2,
    const float* __restrict__ b2, float* __restrict__ out)
{
    int n = blockIdx.x;
    int t = threadIdx.x;
    float x0 = x[(size_t)n * 128 + t];
    float x1 = x[(size_t)n * 128 + 64 + t];
    float p0 = x0 * W2[t * 2]     + x1 * W2[(t + 64) * 2];
    float p1 = x0 * W2[t * 2 + 1] + x1 * W2[(t + 64) * 2 + 1];
    #pragma unroll
    for (int off = 32; off > 0; off >>= 1) {
        p0 += __shfl_down(p0, off);
        p1 += __shfl_down(p1, off);
    }
    if (t == 0) {
        out[(size_t)n * 2]     = p0 + b2[0];
        out[(size_t)n * 2 + 1] = p1 + b2[1];
    }
}

// ---------------------------------------------------------------------------
extern "C" void kernel_launch(void* const* d_in, const int* in_sizes, int n_in,
                              void* d_out, int out_size, void* d_ws, size_t ws_size,
                              hipStream_t stream)
{
    const float* des   = (const float*)d_in[0];
    const float* tw    = (const float*)d_in[1];
    const float* nump  = (const float*)d_in[2];
    const float* catp  = (const float*)d_in[3];
    const float* newf  = (const float*)d_in[4];
    const int*   ei    = (const int*)d_in[5];
    const int*   et    = (const int*)d_in[6];
    const float* Wd    = (const float*)d_in[7];  const float* bd  = (const float*)d_in[8];
    const float* Wt    = (const float*)d_in[9];  const float* bt  = (const float*)d_in[10];
    const float* Wn    = (const float*)d_in[11]; const float* bn  = (const float*)d_in[12];
    const float* Wc    = (const float*)d_in[13]; const float* bc  = (const float*)d_in[14];
    const float* Ww    = (const float*)d_in[15]; const float* bw  = (const float*)d_in[16];
    const float* Win   = (const float*)d_in[17]; const float* bin = (const float*)d_in[18];
    const float* relw1 = (const float*)d_in[19]; const float* rootw1 = (const float*)d_in[20];
    const float* bias1 = (const float*)d_in[21];
    const float* relw2 = (const float*)d_in[22]; const float* rootw2 = (const float*)d_in[23];
    const float* bias2 = (const float*)d_in[24];
    const float* Wo1   = (const float*)d_in[25]; const float* bo1 = (const float*)d_in[26];
    const float* Wo2   = (const float*)d_in[27]; const float* bo2 = (const float*)d_in[28];
    float* outp = (float*)d_out;

    // Workspace layout (~106 MB)
    char* ws = (char*)d_ws;
    const size_t szX = (size_t)NPAD * 128 * sizeof(float);
    float* X0 = (float*)(ws);
    float* X1 = (float*)(ws + szX);
    float* S  = (float*)(ws + 2 * szX);          // NPAD*256 floats (51.25 MB)
    char* p = ws + 2 * szX + (size_t)NPAD * 256 * sizeof(float);
    int* count   = (int*)p; p += (size_t)NPAD * 4;
    int* offsets = (int*)p; p += (size_t)NPAD * 4;
    int* cursor  = (int*)p; p += (size_t)NPAD * 4;
    int* elist   = (int*)p; p += (size_t)N_EDGES * 4;
    int* partial = (int*)p;  // 256 ints

    hipMemsetAsync(count,  0, NPAD * sizeof(int), stream);
    hipMemsetAsync(cursor, 0, NPAD * sizeof(int), stream);

    // Stage 1: feature projections -> xcat (X0), then x1 = lrelu(xcat@W_in+b) (X1)
    dim3 pg(NPAD / 128, 1, 2);
    proj768_wave<<<pg, 256, 0, stream>>>(des, Wd, bd, tw, Wt, bt, X0);
    small_proj_kernel<<<(N_NODES * 75 + 255) / 256, 256, 0, stream>>>(
        nump, catp, newf, Wn, bn, Wc, bc, Ww, bw, X0);
    gemm_v2<128, false, true><<<NPAD / 128, 256, 0, stream>>>(
        X0, nullptr, Win, nullptr, bin, X1);

    // CSR build (once, reused by both RGCN layers)
    count_kernel<<<(N_EDGES + 255) / 256, 256, 0, stream>>>(ei, count);
    scan1_kernel<<<NBLK_SCAN, 256, 0, stream>>>(count, partial);
    scan2_kernel<<<1, 256, 0, stream>>>(partial);
    scan3_kernel<<<NBLK_SCAN, 256, 0, stream>>>(count, partial, offsets);
    fill_kernel<<<(N_EDGES + 255) / 256, 256, 0, stream>>>(ei, et, offsets, cursor, elist);

    // RGCN layer 1: aggregate x1 -> S; x2 = [S|x1] @ [rel_w1; root_w1] + bias1 (X0)
    aggregate_v3<<<(N_NODES + 7) / 8, 256, 0, stream>>>(X1, offsets, count, elist, S);
    gemm_v2<384, true, false><<<NPAD / 128, 256, 0, stream>>>(
        S, X1, relw1, rootw1, bias1, X0);

    // RGCN layer 2: aggregate x2 -> S; x3 = [S|x2] @ [rel_w2; root_w2] + bias2 (X1)
    aggregate_v3<<<(N_NODES + 7) / 8, 256, 0, stream>>>(X0, offsets, count, elist, S);
    gemm_v2<384, true, false><<<NPAD / 128, 256, 0, stream>>>(
        S, X0, relw2, rootw2, bias2, X1);

    // Output head: x4 = lrelu(x3@W_out1+b) (X0); out = x4@W_out2+b
    gemm_v2<128, false, true><<<NPAD / 128, 256, 0, stream>>>(
        X1, nullptr, Wo1, nullptr, bo1, X0);
    final_kernel<<<N_NODES, 64, 0, stream>>>(X0, Wo2, bo2, outp);
}

// Round 3
// 844.264 us; speedup vs baseline: 1.3039x; 1.3039x over previous
//
#include <hip/hip_runtime.h>

// Problem constants
#define N_NODES 50000
#define N_EDGES 600000
#define NPAD    50048          // 782*64 = 391*128, padded row count for tiled GEMMs
#define NBLK_SCAN 196          // ceil(50000/256)

static __device__ __forceinline__ float lrelu(float v) {
    return v > 0.f ? v : 0.01f * v;
}

// ---------------------------------------------------------------------------
// pack_b_kernel: pack Wd (768x25) and Wt (768x28) into col-padded [768][32]
// blocks (zeros in pad cols) + packed biases. Lets the projection run as a
// standard tiled GEMM with aligned float4 B loads. Bp aliases S (dead in
// stage 1).
// ---------------------------------------------------------------------------
__global__ void pack_b_kernel(const float* __restrict__ Wd, const float* __restrict__ bd,
                              const float* __restrict__ Wt, const float* __restrict__ bt,
                              float* __restrict__ Bp, float* __restrict__ biasp)
{
    int id = blockIdx.x * 256 + threadIdx.x;     // 2*768*32 = 49152 total
    if (id < 2 * 768 * 32) {
        int z = id / 24576, rem = id % 24576;
        int k = rem >> 5, j = rem & 31;
        float v = 0.f;
        if (z == 0) { if (j < 25) v = Wd[k * 25 + j]; }
        else        { if (j < 28) v = Wt[k * 28 + j]; }
        Bp[id] = v;
    }
    if (id < 64) {
        int z = id >> 5, j = id & 31;
        float v = 0.f;
        if (z == 0) { if (j < 25) v = bd[j]; }
        else        { if (j < 28) v = bt[j]; }
        biasp[id] = v;
    }
}

// ---------------------------------------------------------------------------
// gemm_proj: [N,768] @ [768,32] using the PROVEN gemm_v2 schedule (stage ->
// sync -> fmac -> sync). Replaces thread-per-row proj768_v4 (TA-bound: 64
// cache lines per load instr at 3KB lane stride) and the failed LDS variants
// (which mixed s_load+ds_read on lgkmcnt -> full drains per k).
//   - tile 128 rows x 32 cols, K-tile 32, K=768; z-dim picks des/tweet
//   - staging: 8 lanes/row -> 16 fully-consumed lines per instr (4x fewer
//     TA line-ops than v4); inner loop PURE ds_read (in-order) + fmac
//   - micro-tile 4x4 (16 acc): 1024 cy compute per K-tile amortizes barriers;
//     LDS read rate 64 B/cy/CU < 85 B/cy ceiling
//   - masked scalar stores to X0 cols [colbase, colbase+NCSTORE)
// ---------------------------------------------------------------------------
template<int NCSTORE>
__device__ __forceinline__ void gemm_proj_body(
    const float* __restrict__ A, const float* __restrict__ B,
    const float* __restrict__ bias, float* __restrict__ X0, int colbase,
    float* __restrict__ AlT, float* __restrict__ Bl)
{
    const int t  = threadIdx.x;
    const int r0 = blockIdx.x * 128;
    const int tx = t & 7, ty = t >> 3;   // 8 col-groups x 32 row-groups

    float acc[4][4] = {};

    for (int k0 = 0; k0 < 768; k0 += 32) {
        // A tile: 128 rows x 32 k = 1024 float4, 4 per thread, store transposed
        #pragma unroll
        for (int i = 0; i < 4; i++) {
            int f4i = t + i * 256;
            int row = f4i >> 3, c4 = f4i & 7;
            int gr = r0 + row;
            if (gr > N_NODES - 1) gr = N_NODES - 1;   // clamp pad rows
            float4 v = *(const float4*)&A[(size_t)gr * 768 + k0 + c4 * 4];
            AlT[(c4 * 4 + 0) * 132 + row] = v.x;
            AlT[(c4 * 4 + 1) * 132 + row] = v.y;
            AlT[(c4 * 4 + 2) * 132 + row] = v.z;
            AlT[(c4 * 4 + 3) * 132 + row] = v.w;
        }
        // B tile: 32 k x 32 cols = 256 float4, 1 per thread
        {
            int kk = t >> 3, c4 = t & 7;
            *(float4*)&Bl[kk * 36 + c4 * 4] =
                *(const float4*)&B[(size_t)(k0 + kk) * 32 + c4 * 4];
        }
        __syncthreads();
        #pragma unroll 4
        for (int k = 0; k < 32; k++) {
            float4 a = *(const float4*)&AlT[k * 132 + ty * 4];
            float4 b = *(const float4*)&Bl [k * 36 + tx * 4];
            float av[4] = {a.x, a.y, a.z, a.w};
            float bv[4] = {b.x, b.y, b.z, b.w};
            #pragma unroll
            for (int i = 0; i < 4; i++)
                #pragma unroll
                for (int j = 0; j < 4; j++) acc[i][j] += av[i] * bv[j];
        }
        __syncthreads();
    }

    #pragma unroll
    for (int j = 0; j < 4; j++) {
        int col = tx * 4 + j;
        if (col < NCSTORE) {
            float bb = bias[col];
            #pragma unroll
            for (int i = 0; i < 4; i++) {
                int row = r0 + ty * 4 + i;
                if (row < N_NODES)
                    X0[(size_t)row * 128 + colbase + col] = lrelu(acc[i][j] + bb);
            }
        }
    }
}

__global__ __launch_bounds__(256, 4) void gemm_proj(
    const float* __restrict__ des, const float* __restrict__ tw,
    const float* __restrict__ Bp, const float* __restrict__ biasp,
    float* __restrict__ X0)
{
    __shared__ float AlT[32 * 132];
    __shared__ float Bl [32 * 36];
    if (blockIdx.z == 0)
        gemm_proj_body<25>(des, Bp,         biasp,      X0, 0,  AlT, Bl);
    else
        gemm_proj_body<28>(tw,  Bp + 24576, biasp + 32, X0, 25, AlT, Bl);
}

// ---------------------------------------------------------------------------
// Small projections: num (K=7 -> cols 53..77), cat (K=11 -> 78..102),
// new_feature (K=1 -> 103..127). One thread per (node, out-col).
// ---------------------------------------------------------------------------
__global__ void small_proj_kernel(
    const float* __restrict__ nump, const float* __restrict__ catp, const float* __restrict__ newf,
    const float* __restrict__ Wn, const float* __restrict__ bn,
    const float* __restrict__ Wc, const float* __restrict__ bc,
    const float* __restrict__ Ww, const float* __restrict__ bw,
    float* __restrict__ out)
{
    int id = blockIdx.x * 256 + threadIdx.x;
    int n = id / 75, c = id % 75;
    if (n >= N_NODES) return;
    float acc; int col;
    if (c < 25) {
        col = 53 + c; acc = bn[c];
        #pragma unroll
        for (int k = 0; k < 7; k++) acc += nump[n * 7 + k] * Wn[k * 25 + c];
    } else if (c < 50) {
        int cc = c - 25; col = 78 + cc; acc = bc[cc];
        #pragma unroll
        for (int k = 0; k < 11; k++) acc += catp[n * 11 + k] * Wc[k * 25 + cc];
    } else {
        int cc = c - 50; col = 103 + cc;
        acc = bw[cc] + newf[n] * Ww[cc];
    }
    out[(size_t)n * 128 + col] = lrelu(acc);
}

// ---------------------------------------------------------------------------
// gemm_v2: tiled fp32 GEMM, 128 out cols. Tile 128 rows x 128 cols, K-tile 32.
// 256 threads as 16x16, 8x8 micro-tile. A stored TRANSPOSED in LDS so the
// inner loop is pure ds_read_b128.
// SPLIT: A = [S (256 wide) | A2 (128 wide)], B = [rel_w (256 rows); root_w].
// ---------------------------------------------------------------------------
template<int KTOT, bool SPLIT, bool ACT>
__global__ __launch_bounds__(256, 4) void gemm_v2(
    const float* __restrict__ A, const float* __restrict__ A2,
    const float* __restrict__ B, const float* __restrict__ B2,
    const float* __restrict__ bias, float* __restrict__ out)
{
    __shared__ float AlT[32 * 132];   // [k][row], row-padded stride 132
    __shared__ float Bl [32 * 132];   // [k][col]
    const int t  = threadIdx.x;
    const int r0 = blockIdx.x * 128;
    const int tx = t & 15, ty = t >> 4;

    float acc[8][8] = {};

    for (int k0 = 0; k0 < KTOT; k0 += 32) {
        // A tile: 128 rows x 32 k = 1024 float4, 4 per thread, store transposed
        #pragma unroll
        for (int i = 0; i < 4; i++) {
            int f4i = t + i * 256;
            int row = f4i >> 3, c4 = f4i & 7;
            int k = k0 + c4 * 4;
            float4 v;
            if (!SPLIT) {
                v = *(const float4*)&A[(size_t)(r0 + row) * 128 + k];
            } else {
                if (k < 256) v = *(const float4*)&A[(size_t)(r0 + row) * 256 + k];
                else         v = *(const float4*)&A2[(size_t)(r0 + row) * 128 + (k - 256)];
            }
            AlT[(c4 * 4 + 0) * 132 + row] = v.x;
            AlT[(c4 * 4 + 1) * 132 + row] = v.y;
            AlT[(c4 * 4 + 2) * 132 + row] = v.z;
            AlT[(c4 * 4 + 3) * 132 + row] = v.w;
        }
        // B tile: 32 k x 128 cols = 1024 float4, 4 per thread
        #pragma unroll
        for (int i = 0; i < 4; i++) {
            int f4i = t + i * 256;
            int kk = f4i >> 5, c4 = f4i & 31;
            int k = k0 + kk;
            float4 v;
            if (!SPLIT) v = *(const float4*)&B[(size_t)k * 128 + c4 * 4];
            else v = (k < 256) ? *(const float4*)&B[(size_t)k * 128 + c4 * 4]
                               : *(const float4*)&B2[(size_t)(k - 256) * 128 + c4 * 4];
            *(float4*)&Bl[kk * 132 + c4 * 4] = v;
        }
        __syncthreads();
        #pragma unroll 4
        for (int k = 0; k < 32; k++) {
            float4 a0 = *(const float4*)&AlT[k * 132 + ty * 8];
            float4 a1 = *(const float4*)&AlT[k * 132 + ty * 8 + 4];
            float4 b0 = *(const float4*)&Bl [k * 132 + tx * 8];
            float4 b1 = *(const float4*)&Bl [k * 132 + tx * 8 + 4];
            float av[8] = {a0.x, a0.y, a0.z, a0.w, a1.x, a1.y, a1.z, a1.w};
            float bv[8] = {b0.x, b0.y, b0.z, b0.w, b1.x, b1.y, b1.z, b1.w};
            #pragma unroll
            for (int i = 0; i < 8; i++)
                #pragma unroll
                for (int j = 0; j < 8; j++) acc[i][j] += av[i] * bv[j];
        }
        __syncthreads();
    }
    float4 bb0 = *(const float4*)&bias[tx * 8];
    float4 bb1 = *(const float4*)&bias[tx * 8 + 4];
    float bb[8] = {bb0.x, bb0.y, bb0.z, bb0.w, bb1.x, bb1.y, bb1.z, bb1.w};
    #pragma unroll
    for (int i = 0; i < 8; i++) {
        size_t row = (size_t)(r0 + ty * 8 + i);
        float o[8];
        #pragma unroll
        for (int j = 0; j < 8; j++) {
            o[j] = acc[i][j] + bb[j];
            if (ACT) o[j] = lrelu(o[j]);
        }
        *(float4*)&out[row * 128 + tx * 8]     = make_float4(o[0], o[1], o[2], o[3]);
        *(float4*)&out[row * 128 + tx * 8 + 4] = make_float4(o[4], o[5], o[6], o[7]);
    }
}

// ---------------------------------------------------------------------------
// CSR build: count, 3-phase exclusive scan, fill (type packed into sign bit).
// ---------------------------------------------------------------------------
__global__ void count_kernel(const int* __restrict__ ei, int* __restrict__ count) {
    int e = blockIdx.x * 256 + threadIdx.x;
    if (e < N_EDGES) atomicAdd(&count[ei[N_EDGES + e]], 1);
}

__global__ void scan1_kernel(const int* __restrict__ count, int* __restrict__ partial) {
    __shared__ int sm[256];
    int b = blockIdx.x, t = threadIdx.x;
    int i = b * 256 + t;
    sm[t] = (i < N_NODES) ? count[i] : 0;
    __syncthreads();
    for (int off = 128; off > 0; off >>= 1) {
        if (t < off) sm[t] += sm[t + off];
        __syncthreads();
    }
    if (t == 0) partial[b] = sm[0];
}

__global__ void scan2_kernel(int* __restrict__ partial) {
    __shared__ int sm[256];
    int t = threadIdx.x;
    int v = (t < NBLK_SCAN) ? partial[t] : 0;
    sm[t] = v; __syncthreads();
    for (int off = 1; off < 256; off <<= 1) {
        int add = (t >= off) ? sm[t - off] : 0;
        __syncthreads();
        sm[t] += add;
        __syncthreads();
    }
    partial[t] = sm[t] - v;   // exclusive
}

__global__ void scan3_kernel(const int* __restrict__ count, const int* __restrict__ partial,
                             int* __restrict__ offsets) {
    __shared__ int sm[256];
    int b = blockIdx.x, t = threadIdx.x;
    int i = b * 256 + t;
    int v = (i < N_NODES) ? count[i] : 0;
    sm[t] = v; __syncthreads();
    for (int off = 1; off < 256; off <<= 1) {
        int add = (t >= off) ? sm[t - off] : 0;
        __syncthreads();
        sm[t] += add;
        __syncthreads();
    }
    if (i < N_NODES) offsets[i] = partial[b] + sm[t] - v;
}

__global__ void fill_kernel(const int* __restrict__ ei, const int* __restrict__ et,
                            const int* __restrict__ offsets, int* __restrict__ cursor,
                            int* __restrict__ elist) {
    int e = blockIdx.x * 256 + threadIdx.x;
    if (e < N_EDGES) {
        int d = ei[N_EDGES + e];
        int pos = atomicAdd(&cursor[d], 1);
        elist[offsets[d] + pos] = (int)(((unsigned)ei[e]) | (((unsigned)et[e]) << 31));
    }
}

// ---------------------------------------------------------------------------
// aggregate_v3: s[n][r][:] = (1/max(deg,1)) * sum_{e:type=r} x[src_e][:]
// 32 lanes per node (float4 each), 8 nodes per 256-thread block.
// 2-edge unroll for memory-level parallelism.
// ---------------------------------------------------------------------------
__global__ __launch_bounds__(256) void aggregate_v3(
    const float* __restrict__ x, const int* __restrict__ offsets,
    const int* __restrict__ count, const int* __restrict__ elist,
    float* __restrict__ s)
{
    int nid  = blockIdx.x * 8 + (threadIdx.x >> 5);
    int lane = threadIdx.x & 31;
    if (nid >= N_NODES) return;
    int start = offsets[nid], dg = count[nid];
    float4 a0 = make_float4(0.f, 0.f, 0.f, 0.f);
    float4 a1 = make_float4(0.f, 0.f, 0.f, 0.f);
    int i = 0;
    for (; i + 2 <= dg; i += 2) {
        int v0 = elist[start + i];
        int v1 = elist[start + i + 1];
        float4 u = ((const float4*)&x[(size_t)(v0 & 0x7FFFFFFF) * 128])[lane];
        float4 w = ((const float4*)&x[(size_t)(v1 & 0x7FFFFFFF) * 128])[lane];
        if (v0 < 0) { a1.x += u.x; a1.y += u.y; a1.z += u.z; a1.w += u.w; }
        else        { a0.x += u.x; a0.y += u.y; a0.z += u.z; a0.w += u.w; }
        if (v1 < 0) { a1.x += w.x; a1.y += w.y; a1.z += w.z; a1.w += w.w; }
        else        { a0.x += w.x; a0.y += w.y; a0.z += w.z; a0.w += w.w; }
    }
    if (i < dg) {
        int v0 = elist[start + i];
        float4 u = ((const float4*)&x[(size_t)(v0 & 0x7FFFFFFF) * 128])[lane];
        if (v0 < 0) { a1.x += u.x; a1.y += u.y; a1.z += u.z; a1.w += u.w; }
        else        { a0.x += u.x; a0.y += u.y; a0.z += u.z; a0.w += u.w; }
    }
    float inv = 1.0f / (float)(dg > 0 ? dg : 1);
    a0.x *= inv; a0.y *= inv; a0.z *= inv; a0.w *= inv;
    a1.x *= inv; a1.y *= inv; a1.z *= inv; a1.w *= inv;
    ((float4*)&s[(size_t)nid * 256])[lane]       = a0;
    ((float4*)&s[(size_t)nid * 256 + 128])[lane] = a1;
}

// ---------------------------------------------------------------------------
// Final: out[n][0:2] = x4[n] @ W_out2 + b_out2. One wave per node.
// ---------------------------------------------------------------------------
__global__ __launch_bounds__(64) void final_kernel(
    const float* __restrict__ x, const float* __restrict__ W2,
    const float* __restrict__ b2, float* __restrict__ out)
{
    int n = blockIdx.x;
    int t = threadIdx.x;
    float x0 = x[(size_t)n * 128 + t];
    float x1 = x[(size_t)n * 128 + 64 + t];
    float p0 = x0 * W2[t * 2]     + x1 * W2[(t + 64) * 2];
    float p1 = x0 * W2[t * 2 + 1] + x1 * W2[(t + 64) * 2 + 1];
    #pragma unroll
    for (int off = 32; off > 0; off >>= 1) {
        p0 += __shfl_down(p0, off);
        p1 += __shfl_down(p1, off);
    }
    if (t == 0) {
        out[(size_t)n * 2]     = p0 + b2[0];
        out[(size_t)n * 2 + 1] = p1 + b2[1];
    }
}

// ---------------------------------------------------------------------------
extern "C" void kernel_launch(void* const* d_in, const int* in_sizes, int n_in,
                              void* d_out, int out_size, void* d_ws, size_t ws_size,
                              hipStream_t stream)
{
    const float* des   = (const float*)d_in[0];
    const float* tw    = (const float*)d_in[1];
    const float* nump  = (const float*)d_in[2];
    const float* catp  = (const float*)d_in[3];
    const float* newf  = (const float*)d_in[4];
    const int*   ei    = (const int*)d_in[5];
    const int*   et    = (const int*)d_in[6];
    const float* Wd    = (const float*)d_in[7];  const float* bd  = (const float*)d_in[8];
    const float* Wt    = (const float*)d_in[9];  const float* bt  = (const float*)d_in[10];
    const float* Wn    = (const float*)d_in[11]; const float* bn  = (const float*)d_in[12];
    const float* Wc    = (const float*)d_in[13]; const float* bc  = (const float*)d_in[14];
    const float* Ww    = (const float*)d_in[15]; const float* bw  = (const float*)d_in[16];
    const float* Win   = (const float*)d_in[17]; const float* bin = (const float*)d_in[18];
    const float* relw1 = (const float*)d_in[19]; const float* rootw1 = (const float*)d_in[20];
    const float* bias1 = (const float*)d_in[21];
    const float* relw2 = (const float*)d_in[22]; const float* rootw2 = (const float*)d_in[23];
    const float* bias2 = (const float*)d_in[24];
    const float* Wo1   = (const float*)d_in[25]; const float* bo1 = (const float*)d_in[26];
    const float* Wo2   = (const float*)d_in[27]; const float* bo2 = (const float*)d_in[28];
    float* outp = (float*)d_out;

    // Workspace layout (~105.8 MB)
    char* ws = (char*)d_ws;
    const size_t szX = (size_t)NPAD * 128 * sizeof(float);
    float* X0 = (float*)(ws);
    float* X1 = (float*)(ws + szX);
    float* S  = (float*)(ws + 2 * szX);          // NPAD*256 floats (51.25 MB)
    // Bp (packed proj weights, 2*768*32 floats + 64 bias) aliases S;
    // Bp is dead before the first aggregate writes S.
    float* Bp    = S;
    float* biasp = S + 2 * 768 * 32;
    char* p = ws + 2 * szX + (size_t)NPAD * 256 * sizeof(float);
    int* count   = (int*)p; p += (size_t)NPAD * 4;
    int* offsets = (int*)p; p += (size_t)NPAD * 4;
    int* cursor  = (int*)p; p += (size_t)NPAD * 4;
    int* elist   = (int*)p; p += (size_t)N_EDGES * 4;
    int* partial = (int*)p;  // 256 ints

    hipMemsetAsync(count,  0, NPAD * sizeof(int), stream);
    hipMemsetAsync(cursor, 0, NPAD * sizeof(int), stream);

    // Stage 1: feature projections -> xcat (X0), then x1 = lrelu(xcat@W_in+b) (X1)
    pack_b_kernel<<<192, 256, 0, stream>>>(Wd, bd, Wt, bt, Bp, biasp);
    dim3 pg(NPAD / 128, 1, 2);
    gemm_proj<<<pg, 256, 0, stream>>>(des, tw, Bp, biasp, X0);
    small_proj_kernel<<<(N_NODES * 75 + 255) / 256, 256, 0, stream>>>(
        nump, catp, newf, Wn, bn, Wc, bc, Ww, bw, X0);
    gemm_v2<128, false, true><<<NPAD / 128, 256, 0, stream>>>(
        X0, nullptr, Win, nullptr, bin, X1);

    // CSR build (once, reused by both RGCN layers)
    count_kernel<<<(N_EDGES + 255) / 256, 256, 0, stream>>>(ei, count);
    scan1_kernel<<<NBLK_SCAN, 256, 0, stream>>>(count, partial);
    scan2_kernel<<<1, 256, 0, stream>>>(partial);
    scan3_kernel<<<NBLK_SCAN, 256, 0, stream>>>(count, partial, offsets);
    fill_kernel<<<(N_EDGES + 255) / 256, 256, 0, stream>>>(ei, et, offsets, cursor, elist);

    // RGCN layer 1: aggregate x1 -> S; x2 = [S|x1] @ [rel_w1; root_w1] + bias1 (X0)
    aggregate_v3<<<(N_NODES + 7) / 8, 256, 0, stream>>>(X1, offsets, count, elist, S);
    gemm_v2<384, true, false><<<NPAD / 128, 256, 0, stream>>>(
        S, X1, relw1, rootw1, bias1, X0);

    // RGCN layer 2: aggregate x2 -> S; x3 = [S|x2] @ [rel_w2; root_w2] + bias2 (X1)
    aggregate_v3<<<(N_NODES + 7) / 8, 256, 0, stream>>>(X0, offsets, count, elist, S);
    gemm_v2<384, true, false><<<NPAD / 128, 256, 0, stream>>>(
        S, X0, relw2, rootw2, bias2, X1);

    // Output head: x4 = lrelu(x3@W_out1+b) (X0); out = x4@W_out2+b
    gemm_v2<128, false, true><<<NPAD / 128, 256, 0, stream>>>(
        X1, nullptr, Wo1, nullptr, bo1, X0);
    final_kernel<<<N_NODES, 64, 0, stream>>>(X0, Wo2, bo2, outp);
}